// Round 16
// baseline (282.137 us; speedup 1.0000x reference)
//
#include <hip/hip_runtime.h>

#define B_  8
#define C_  128
#define H_  128
#define W_  256
#define HW_ (H_ * W_)
#define TH  8
#define TW  32
#define NPAIR 4                    // channel-pairs per stage (8 channels/stage)
#define F2RS 72                    // f2 row stride (dw)
#define F2PT (16 * F2RS)           // 1152 dw per f2 pair-tile (16 rows)
#define F1RS 40                    // f1 row stride (dw): 2-way banks (free)
#define F1PT (8 * F1RS)            // 320 dw per f1 pair-tile
#define F1OFF (NPAIR * F2PT)       // 4608
#define BUFN (F1OFF + NPAIR * F1PT) // 5888 dw per buffer (23 KB; dbuf 46 KB)
#define NTHREADS 512

typedef __fp16 h2 __attribute__((ext_vector_type(2)));

__device__ __forceinline__ float dot2f16(unsigned int a, unsigned int b, float c) {
#if __has_builtin(__builtin_amdgcn_fdot2)
    return __builtin_amdgcn_fdot2(__builtin_bit_cast(h2, a),
                                  __builtin_bit_cast(h2, b), c, false);
#else
    h2 ha = __builtin_bit_cast(h2, a), hb = __builtin_bit_cast(h2, b);
    return c + (float)ha.x * (float)hb.x + (float)ha.y * (float)hb.y;
#endif
}

__device__ __forceinline__ unsigned int pk(float x, float y) {
    h2 r = __builtin_amdgcn_cvt_pkrtz(x, y);
    return __builtin_bit_cast(unsigned int, r);
}

// r9 economics repartitioned: 8-wave block (512 thr) so TWO blocks co-reside
// per CU (16 waves = 4/SIMD at the 128-reg cap; 2x46KB LDS). Tile 8h x 32w.
// Wave w = di (0..7), lane = (row hh, 4-px strip sc), acc[9dj][4px] = 36.
// di=8 plane-set folded into waves 0,1: acc8[9dj][2px] (+3 LDS reads/pair,
// same f2 tile rows, same f1u). Staging map identical to r9; all threads work.
// Depth-1.5 pipeline, raw s_barrier + lgkmcnt(0) (counted vmcnt on loads).
__global__ __launch_bounds__(NTHREADS, 4) void cv_kernel(
    const float* __restrict__ f1g, const float* __restrict__ f2g,
    float* __restrict__ outg) {
    __shared__ __align__(16) unsigned int lds[2][BUFN];

    const int tid = threadIdx.x;
    const int w0 = blockIdx.x * TW;
    const int h0 = blockIdx.y * TH;
    const int b  = blockIdx.z;

    // ---- slot A (all 512): f2 primary, 4 pairs x 16 rows x units 0..7 ----
    int offA, ldA;
    float mA;
    {
        int pp = tid >> 7, r = (tid >> 3) & 15, u = tid & 7;
        int gh = h0 - 4 + r, gw = w0 - 4 + 4 * u;
        bool valid = (gh >= 0) && (gh < H_) && (gw >= 0) && (gw <= W_ - 4);
        int ghc = min(max(gh, 0), H_ - 1);
        int gwc = min(max(gw, 0), W_ - 4);
        offA = ((b * C_ + 2 * pp) * H_ + ghc) * W_ + gwc;
        ldA  = pp * F2PT + r * F2RS + 4 * u;
        mA   = valid ? 1.f : 0.f;
    }
    // ---- slot C: tid<128 -> f2 units 8,9; tid 128..383 -> f1 ----
    const bool roleC = (tid < 384);
    int offC = 0, ldC = 0;
    float mC = 0.f;
    const float* pC = f1g;
    if (tid < 128) {               // f2 u89
        int pp = tid >> 5, r = (tid >> 1) & 15, u = 8 + (tid & 1);
        int gh = h0 - 4 + r, gw = w0 - 4 + 4 * u;
        bool valid = (gh >= 0) && (gh < H_) && (gw >= 0) && (gw <= W_ - 4);
        int ghc = min(max(gh, 0), H_ - 1);
        int gwc = min(max(gw, 0), W_ - 4);
        offC = ((b * C_ + 2 * pp) * H_ + ghc) * W_ + gwc;
        pC   = f2g;
        ldC  = pp * F2PT + r * F2RS + 4 * u;
        mC   = valid ? 1.f : 0.f;
    } else if (tid < 384) {        // f1: 4 pairs x 8 rows x 8 units
        int t = tid - 128;
        int pp = t >> 6, r = (t >> 3) & 7, u = t & 7;
        offC = ((b * C_ + 2 * pp) * H_ + h0 + r) * W_ + w0 + 4 * u;
        pC   = f1g;
        ldC  = F1OFF + pp * F1PT + r * F1RS + 4 * u;
        mC   = 1.f;
    }

#define LOADST()                                                              \
    do {                                                                      \
        aA = *(const float4*)(f2g + offA);                                    \
        bA = *(const float4*)(f2g + offA + HW_);                              \
        offA += 8 * HW_;                                                      \
        if (roleC) {                                                          \
            cC = *(const float4*)(pC + offC);                                 \
            dC = *(const float4*)(pC + offC + HW_);                           \
            offC += 8 * HW_;                                                  \
        }                                                                     \
    } while (0)

#define STOREST(bi)                                                           \
    do {                                                                      \
        uint4 wv;                                                             \
        wv.x = pk(aA.x * mA, bA.x * mA);                                      \
        wv.y = pk(aA.y * mA, bA.y * mA);                                      \
        wv.z = pk(aA.z * mA, bA.z * mA);                                      \
        wv.w = pk(aA.w * mA, bA.w * mA);                                      \
        *(uint4*)(&lds[bi][ldA]) = wv;                                        \
        if (roleC) {                                                          \
            uint4 w2;                                                         \
            w2.x = pk(cC.x * mC, dC.x * mC);                                  \
            w2.y = pk(cC.y * mC, dC.y * mC);                                  \
            w2.z = pk(cC.z * mC, dC.z * mC);                                  \
            w2.w = pk(cC.w * mC, dC.w * mC);                                  \
            *(uint4*)(&lds[bi][ldC]) = w2;                                    \
        }                                                                     \
    } while (0)

#define BAR()                                                                 \
    do {                                                                      \
        asm volatile("s_waitcnt lgkmcnt(0)" ::: "memory");                    \
        __builtin_amdgcn_s_barrier();                                         \
    } while (0)

    // ---- compute mapping ----
    const int di   = tid >> 6;       // 0..7 (primary di)
    const int lane = tid & 63;
    const int hh   = lane >> 3;      // 0..7
    const int sc   = lane & 7;       // 0..7, 4-px strip
    const int rd0  = (hh + di) * F2RS + 4 * sc;          // primary f2 row
    const int rd8  = (hh + 8) * F2RS + 4 * sc;           // di=8 f2 row
    const int rf0  = F1OFF + hh * F1RS + 4 * sc;         // f1 unit sc
    const bool sec = (di < 2);
    const int pxb  = 2 * di;         // secondary px offset (0 or 2)

    float acc[9][4];
#pragma unroll
    for (int j = 0; j < 9; ++j)
#pragma unroll
        for (int p = 0; p < 4; ++p) acc[j][p] = 0.f;
    float acc8[9][2];
#pragma unroll
    for (int j = 0; j < 9; ++j) { acc8[j][0] = 0.f; acc8[j][1] = 0.f; }

#define COMPUTE(bi)                                                           \
    do {                                                                      \
        _Pragma("unroll 2")                                                   \
        for (int q = 0; q < NPAIR; ++q) {                                     \
            const unsigned int* bf2 = &lds[bi][q * F2PT];                     \
            const unsigned int* bf1 = &lds[bi][q * F1PT];                     \
            uint4 ga = *(const uint4*)(bf1 + rf0);                            \
            unsigned int f1u[4] = {ga.x, ga.y, ga.z, ga.w};                   \
            {                                                                 \
                uint4 fa = *(const uint4*)(bf2 + rd0);                        \
                uint4 fb = *(const uint4*)(bf2 + rd0 + 4);                    \
                uint4 fc = *(const uint4*)(bf2 + rd0 + 8);                    \
                unsigned int f2u[12] = {fa.x, fa.y, fa.z, fa.w,               \
                                        fb.x, fb.y, fb.z, fb.w,               \
                                        fc.x, fc.y, fc.z, fc.w};              \
                _Pragma("unroll")                                             \
                for (int j = 0; j < 9; ++j)                                   \
                    _Pragma("unroll")                                         \
                    for (int p = 0; p < 4; ++p)                               \
                        acc[j][p] = dot2f16(f1u[p], f2u[p + j], acc[j][p]);   \
            }                                                                 \
            if (sec) {                                                        \
                uint4 fa = *(const uint4*)(bf2 + rd8);                        \
                uint4 fb = *(const uint4*)(bf2 + rd8 + 4);                    \
                uint4 fc = *(const uint4*)(bf2 + rd8 + 8);                    \
                unsigned int f2u[12] = {fa.x, fa.y, fa.z, fa.w,               \
                                        fb.x, fb.y, fb.z, fb.w,               \
                                        fc.x, fc.y, fc.z, fc.w};              \
                _Pragma("unroll")                                             \
                for (int j = 0; j < 9; ++j)                                   \
                    _Pragma("unroll")                                         \
                    for (int p = 0; p < 2; ++p)                               \
                        acc8[j][p] = dot2f16(f1u[pxb + p],                    \
                                             f2u[pxb + p + j], acc8[j][p]);   \
            }                                                                 \
        }                                                                     \
    } while (0)

    float4 aA, bA, cC, dC;

    // prologue: stage 0 -> buf0
    LOADST();
    STOREST(0);
    BAR();

    // 16 stages of 8 channels, depth-1.5
    for (int st = 0; st < 14; st += 2) {
        LOADST();                    // stage st+1 (in flight over compute)
        COMPUTE(0);                  // stage st
        STOREST(1);                  // stage st+1 (counted vmcnt)
        BAR();
        LOADST();                    // stage st+2
        COMPUTE(1);                  // stage st+1
        STOREST(0);                  // stage st+2
        BAR();
    }
    LOADST();                        // stage 15
    COMPUTE(0);                      // stage 14
    STOREST(1);                      // stage 15
    BAR();
    COMPUTE(1);                      // stage 15

    // ---- epilogue ----
    const float inv = 1.0f / 128.0f;
    int obase = ((b * 81 + di * 9) * H_ + h0 + hh) * W_ + w0 + 4 * sc;
#pragma unroll
    for (int j = 0; j < 9; ++j) {
        float4 o = make_float4(acc[j][0] * inv, acc[j][1] * inv,
                               acc[j][2] * inv, acc[j][3] * inv);
        *(float4*)(outg + obase) = o;
        obase += HW_;
    }
    if (sec) {
        int o8 = ((b * 81 + 72) * H_ + h0 + hh) * W_ + w0 + 4 * sc + pxb;
#pragma unroll
        for (int j = 0; j < 9; ++j) {
            outg[o8]     = acc8[j][0] * inv;
            outg[o8 + 1] = acc8[j][1] * inv;
            o8 += HW_;
        }
    }
}

extern "C" void kernel_launch(void* const* d_in, const int* in_sizes, int n_in,
                              void* d_out, int out_size, void* d_ws, size_t ws_size,
                              hipStream_t stream) {
    const float* f1 = (const float*)d_in[0];
    const float* f2 = (const float*)d_in[1];
    float* out = (float*)d_out;
    dim3 grid(W_ / TW, H_ / TH, B_);   // 8 x 16 x 8 = 1024 blocks
    cv_kernel<<<grid, NTHREADS, 0, stream>>>(f1, f2, out);
}